// Round 8
// baseline (2758.290 us; speedup 1.0000x reference)
//
#include <hip/hip_runtime.h>
#include <hip/hip_bf16.h>
#include <stdint.h>

typedef _Float16 f16x8 __attribute__((ext_vector_type(8)));
typedef float f32x4 __attribute__((ext_vector_type(4)));
typedef unsigned long long u64;
typedef unsigned int u32;

#define N_CODES 16384
#define N_VEC   16384

#define OUT_LOSS_OFF 4194304
#define OUT_IDX_OFF  4194305

// ws layout (bytes). High-water mark 17,565,712 B == proven extent. DO NOT GROW.
#define WS_EHI   0u          // 8,388,608
#define WS_ELO   8388608u    // 8,388,608
#define WS_E2    16777216u   // 65,536
#define WS_SCR   16842752u   // u32 [8 splits][16384 rows] = 524,288
#define WS_FKEY  17367040u   // u64 [16384] = 131,072
#define WS_COUNT 17498112u   // 16
#define WS_LIST  17498128u   // 512 ints = 2,048
#define WS_FBIT  17500176u   // 16384 u32 = 65,536 -> ends 17,565,712

#define MARGIN 4.0e-3f
#define CAP 512

#define A_STRIDE 264                        // 256 + 8 pad (f16 units), prologue only
// Loop overlay: S0 slab [0,32K), S1 slab [32K,64K), e2s [64K,72K). Slab = 32 codes
// x 256 k, hi half [0,16K) + lo half [16K,32K), 512 B/code-row, 16B chunks
// XOR-swizzled (chunk ^= row&7) -> every ds phase is 2-way (free, m136).
#define LDS_BYTES 73728                     // -> 2 blocks/CU (147456 <= 163840)

__device__ __forceinline__ u32 sortable_from_f32(float f) {
  u32 u = __float_as_uint(f);
  return (u & 0x80000000u) ? ~u : (u | 0x80000000u);
}
__device__ __forceinline__ float f32_from_sortable(u32 s) {
  u32 u = (s & 0x80000000u) ? (s & 0x7FFFFFFFu) : ~s;
  return __uint_as_float(u);
}

__device__ __forceinline__ void flag_row(int row, int* count, int* list, u32* fbit) {
  if (atomicExch(&fbit[row], 1u) == 0u) {
    const int p = atomicAdd(count, 1);
    if (p < CAP) list[p] = row;
  }
}

// ---------------- prep: embedding -> f16 hi/lo + exact ||e||^2 + state init ----------------
__global__ __launch_bounds__(256) void k_prep(const float* __restrict__ emb,
                                              _Float16* __restrict__ ehi,
                                              _Float16* __restrict__ elo,
                                              float* __restrict__ e2,
                                              u64* __restrict__ fkey,
                                              u32* __restrict__ fbit,
                                              int* __restrict__ count) {
  const int g = blockIdx.x * 256 + threadIdx.x;
  if (g < N_VEC) { fkey[g] = ~0ull; fbit[g] = 0u; }
  if (g == N_VEC) { count[0] = 0; }
  const int code = blockIdx.x * 4 + (threadIdx.x >> 6);
  const int lane = threadIdx.x & 63;
  const float4 v = ((const float4*)emb)[code * 64 + lane];
  union { _Float16 f[4]; uint2 u2; } ph, pl;
  float vv[4] = {v.x, v.y, v.z, v.w};
  double s = 0.0;
#pragma unroll
  for (int j = 0; j < 4; ++j) {
    _Float16 h = (_Float16)vv[j];
    _Float16 l = (_Float16)(vv[j] - (float)h);
    ph.f[j] = h; pl.f[j] = l;
    s += (double)vv[j] * (double)vv[j];
  }
  ((uint2*)ehi)[code * 64 + lane] = ph.u2;
  ((uint2*)elo)[code * 64 + lane] = pl.u2;
#pragma unroll
  for (int off = 32; off; off >>= 1) s += __shfl_down(s, off);
  if (lane == 0) e2[code] = (float)s;
}

// ---------------- main fused GEMM + per-split argmin ----------------
// grid 1024: split = blockIdx & 7 (2048 codes, XCD-pinned), row tile = blockIdx >> 3.
// Tile-granular double-buffered B slabs (32 KB: 32 codes x K=256, hi+lo), ONE barrier
// per tile (vs per-step in r7). 8 uint4 global loads/thread issued one full tile ahead.
// Epilogue: cheap f32 min + idx + sticky near-tie flag per lane (u64 top-2 only in the
// final cross-lane reduce). A-hi/A-lo fragments in statically-indexed registers.
__global__ __launch_bounds__(256, 2) void k_gemm(const float* __restrict__ z,
                                                 const _Float16* __restrict__ ehi,
                                                 const _Float16* __restrict__ elo,
                                                 const float* __restrict__ e2,
                                                 u32* __restrict__ scr,
                                                 u64* __restrict__ fkey,
                                                 int* __restrict__ count,
                                                 int* __restrict__ list,
                                                 u32* __restrict__ fbit) {
  extern __shared__ char smem_raw[];
  _Float16* Asm = (_Float16*)smem_raw;       // prologue A staging (overlaps slabs)
  char* S0 = smem_raw;
  char* S1 = smem_raw + 32768;
  float* e2s = (float*)(smem_raw + 65536);   // 8 KB

  const int tid = threadIdx.x;
  const int split = blockIdx.x & 7;
  const int rt = blockIdx.x >> 3;
  const int row0 = rt * 128;
  const int bb = row0 >> 10, hw0 = row0 & 1023;
  const int cb0 = split * 2048;

  const float4* z4 = (const float4*)z;
  const int lane = tid & 63, w = tid >> 6;
  const int fr = lane & 15, q = lane >> 4;
  const int rbase = w * 32;

  // ---- B staging thread mapping: 4 (row,c) pairs, staged for hi and lo halves ----
  u32 gidx[4], wo[4];
#pragma unroll
  for (int j = 0; j < 4; ++j) {
    const u32 flat = (u32)(j * 256 + tid);   // 0..1023
    const u32 row = flat >> 5;               // 0..31
    const u32 c = flat & 31;                 // 0..31 (16B chunk within row)
    gidx[j] = (u32)(cb0 + (int)row) * 32u + c;             // uint4 units
    wo[j] = row * 512u + ((c ^ (row & 7u)) << 4);          // swizzled byte off in half
  }
  const uint4* EH4 = (const uint4*)ehi;
  const uint4* EL4 = (const uint4*)elo;

  uint4 ph[4], pl[4];
  // tile 0 loads in flight across the whole A prologue
#pragma unroll
  for (int j = 0; j < 4; ++j) { ph[j] = EH4[gidx[j]]; pl[j] = EL4[gidx[j]]; }

  f16x8 ah[2][8], al[2][8];

  // ---- phase 1: stage A-hi tile (128 rows x 256 dims), NCHW transpose ----
  {
    const int fq = tid & 31, cg = tid >> 5;
    for (int i = 0; i < 32; ++i) {
      const int c = i * 8 + cg;
      float4 v = z4[(bb * 256 + c) * 256 + (hw0 >> 2) + fq];
      float vv[4] = {v.x, v.y, v.z, v.w};
      const int r = fq * 4;
#pragma unroll
      for (int j = 0; j < 4; ++j)
        Asm[(r + j) * A_STRIDE + c] = (_Float16)vv[j];
    }
  }
  __syncthreads();
#pragma unroll
  for (int mf = 0; mf < 2; ++mf)
#pragma unroll
    for (int kc = 0; kc < 8; ++kc)
      ah[mf][kc] = *(const f16x8*)&Asm[(rbase + mf * 16 + fr) * A_STRIDE + kc * 32 + q * 8];
  __syncthreads();

  // ---- phase 2: stage A-lo, load fragments ----
  {
    const int fq = tid & 31, cg = tid >> 5;
    for (int i = 0; i < 32; ++i) {
      const int c = i * 8 + cg;
      float4 v = z4[(bb * 256 + c) * 256 + (hw0 >> 2) + fq];
      float vv[4] = {v.x, v.y, v.z, v.w};
      const int r = fq * 4;
#pragma unroll
      for (int j = 0; j < 4; ++j) {
        float f = vv[j];
        _Float16 h = (_Float16)f;
        Asm[(r + j) * A_STRIDE + c] = (_Float16)(f - (float)h);
      }
    }
  }
  __syncthreads();
#pragma unroll
  for (int mf = 0; mf < 2; ++mf)
#pragma unroll
    for (int kc = 0; kc < 8; ++kc)
      al[mf][kc] = *(const f16x8*)&Asm[(rbase + mf * 16 + fr) * A_STRIDE + kc * 32 + q * 8];
  __syncthreads();   // all A reads done before slab/e2 overlay writes

  // ---- overlay prologue: e2 slice, slab 0 commit, tile-1 loads ----
  {
    const float4* e24 = (const float4*)(e2 + cb0);
#pragma unroll
    for (int j = 0; j < 2; ++j)
      ((float4*)e2s)[tid + j * 256] = e24[tid + j * 256];
  }
#pragma unroll
  for (int j = 0; j < 4; ++j) {
    *(uint4*)(S0 + wo[j]) = ph[j];
    *(uint4*)(S0 + 16384 + wo[j]) = pl[j];
  }
#pragma unroll
  for (int j = 0; j < 4; ++j) { ph[j] = EH4[gidx[j] + 1024u]; pl[j] = EL4[gidx[j] + 1024u]; }
  __syncthreads();

  // ---- per-lane argmin state (cheap f32 path) ----
  f32x4 acc[2][2] = {};
  float f1[2][4]; u32 bidx[2][4], bflg[2][4];
#pragma unroll
  for (int mf = 0; mf < 2; ++mf)
#pragma unroll
    for (int rg = 0; rg < 4; ++rg) { f1[mf][rg] = 1e30f; bidx[mf][rg] = 0u; bflg[mf][rg] = 0u; }

  // LDS read swizzle precompute: chunk = (kc*4+q) ^ (fr&7), decomposed (no carries)
  const u32 qx = (u32)((q ^ (fr & 3)) << 4);       // low part of swizzled chunk, bytes
  const int kx = (fr >> 2) & 1;                    // flips kc bit0
  const u32 ro0 = (u32)fr * 512u;
  const u32 ro1 = (u32)(fr + 16) * 512u;

  // ---- code sweep: 64 tiles of 32 codes; one barrier per tile ----
  for (int t = 0; t < 64; ++t) {
    const char* Br = (t & 1) ? S1 : S0;
    char* Bw = (t & 1) ? S0 : S1;

    if (t < 63) {
#pragma unroll
      for (int j = 0; j < 4; ++j) {
        *(uint4*)(Bw + wo[j]) = ph[j];
        *(uint4*)(Bw + 16384 + wo[j]) = pl[j];
      }
    }
    if (t < 62) {
      const u32 goff = (u32)(t + 2) * 1024u;
#pragma unroll
      for (int j = 0; j < 4; ++j) { ph[j] = EH4[gidx[j] + goff]; pl[j] = EL4[gidx[j] + goff]; }
    }

#pragma unroll
    for (int kc = 0; kc < 8; ++kc) {
      const u32 off = (u32)(((kc ^ kx) << 6)) + qx;
      const f16x8 bh0 = *(const f16x8*)(Br + ro0 + off);
      const f16x8 bh1 = *(const f16x8*)(Br + ro1 + off);
      const f16x8 bl0 = *(const f16x8*)(Br + 16384 + ro0 + off);
      const f16x8 bl1 = *(const f16x8*)(Br + 16384 + ro1 + off);
      const f16x8 ah0 = ah[0][kc], ah1 = ah[1][kc];
      const f16x8 al0 = al[0][kc], al1 = al[1][kc];

      acc[0][0] = __builtin_amdgcn_mfma_f32_16x16x32_f16(ah0, bh0, acc[0][0], 0, 0, 0);
      acc[0][0] = __builtin_amdgcn_mfma_f32_16x16x32_f16(al0, bh0, acc[0][0], 0, 0, 0);
      acc[0][0] = __builtin_amdgcn_mfma_f32_16x16x32_f16(ah0, bl0, acc[0][0], 0, 0, 0);
      acc[0][1] = __builtin_amdgcn_mfma_f32_16x16x32_f16(ah0, bh1, acc[0][1], 0, 0, 0);
      acc[0][1] = __builtin_amdgcn_mfma_f32_16x16x32_f16(al0, bh1, acc[0][1], 0, 0, 0);
      acc[0][1] = __builtin_amdgcn_mfma_f32_16x16x32_f16(ah0, bl1, acc[0][1], 0, 0, 0);
      acc[1][0] = __builtin_amdgcn_mfma_f32_16x16x32_f16(ah1, bh0, acc[1][0], 0, 0, 0);
      acc[1][0] = __builtin_amdgcn_mfma_f32_16x16x32_f16(al1, bh0, acc[1][0], 0, 0, 0);
      acc[1][0] = __builtin_amdgcn_mfma_f32_16x16x32_f16(ah1, bl0, acc[1][0], 0, 0, 0);
      acc[1][1] = __builtin_amdgcn_mfma_f32_16x16x32_f16(ah1, bh1, acc[1][1], 0, 0, 0);
      acc[1][1] = __builtin_amdgcn_mfma_f32_16x16x32_f16(al1, bh1, acc[1][1], 0, 0, 0);
      acc[1][1] = __builtin_amdgcn_mfma_f32_16x16x32_f16(ah1, bl1, acc[1][1], 0, 0, 0);
    }

    // epilogue: s = ||e||^2 - 2*dot; f32 min + idx + sticky near-tie flag.
    // Processing order (t asc, nf0 then nf1) is ascending code order -> strict '<'
    // keeps first occurrence; exact ties are flagged (d==0 < MARGIN) and rescued.
    {
      const float ev0 = e2s[t * 32 + fr];
      const float ev1 = e2s[t * 32 + 16 + fr];
      const u32 g0 = (u32)(cb0 + t * 32 + fr);
#pragma unroll
      for (int mf = 0; mf < 2; ++mf) {
#pragma unroll
        for (int rg = 0; rg < 4; ++rg) {
          float s0 = fmaf(-2.0f, acc[mf][0][rg], ev0);
          float d0 = s0 - f1[mf][rg];
          bflg[mf][rg] = (fabsf(d0) < MARGIN) ? 1u : bflg[mf][rg];
          bool lt0 = s0 < f1[mf][rg];
          bidx[mf][rg] = lt0 ? g0 : bidx[mf][rg];
          f1[mf][rg] = lt0 ? s0 : f1[mf][rg];

          float s1 = fmaf(-2.0f, acc[mf][1][rg], ev1);
          float d1 = s1 - f1[mf][rg];
          bflg[mf][rg] = (fabsf(d1) < MARGIN) ? 1u : bflg[mf][rg];
          bool lt1 = s1 < f1[mf][rg];
          bidx[mf][rg] = lt1 ? (g0 + 16u) : bidx[mf][rg];
          f1[mf][rg] = lt1 ? s1 : f1[mf][rg];
        }
      }
#pragma unroll
      for (int mf = 0; mf < 2; ++mf)
#pragma unroll
        for (int nf = 0; nf < 2; ++nf) acc[mf][nf] = (f32x4){0.0f, 0.0f, 0.0f, 0.0f};
    }

    __syncthreads();   // one barrier/tile: slab write-visibility + read-before-overwrite
  }

  // ---- cross-lane reduce (16 column-lanes): u64 top-2 of per-lane mins + flag OR ----
#pragma unroll
  for (int mf = 0; mf < 2; ++mf) {
#pragma unroll
    for (int rg = 0; rg < 4; ++rg) {
      u64 a1 = ((u64)sortable_from_f32(f1[mf][rg]) << 32) | bidx[mf][rg];
      u64 a2 = ~0ull;
      u32 fl = bflg[mf][rg];
#pragma unroll
      for (int off = 1; off < 16; off <<= 1) {
        u64 b1 = __shfl_xor(a1, off);
        u64 b2 = __shfl_xor(a2, off);
        fl |= (u32)__shfl_xor((int)fl, off);
        u64 n1 = a1 < b1 ? a1 : b1;
        u64 mx = a1 < b1 ? b1 : a1;
        u64 mn2 = a2 < b2 ? a2 : b2;
        a1 = n1;
        a2 = mx < mn2 ? mx : mn2;
      }
      if (fr == 0) {
        const int row = row0 + rbase + mf * 16 + q * 4 + rg;
        scr[split * N_VEC + row] = (u32)(a1 >> 32);
        atomicMin(&fkey[row], a1);
        const float s1 = f32_from_sortable((u32)(a1 >> 32));
        const float s2 = f32_from_sortable((u32)(a2 >> 32));
        if ((s2 - s1 < MARGIN) || fl) flag_row(row, count, list, fbit);
      }
    }
  }
}

// ---------------- merge: flag cross-split near-ties (non-destructive) ----------------
// fkey keeps the gemm atomicMin result; rescue keys are numerically always smaller
// than gemm keys, so a rescued row's exact key wins and an un-rescued flagged row
// (CAP overflow) gracefully keeps the gemm argmin.
__global__ __launch_bounds__(256) void k_merge(const u32* __restrict__ scr,
                                               u64* __restrict__ fkey,
                                               int* __restrict__ count,
                                               int* __restrict__ list,
                                               u32* __restrict__ fbit) {
  const int r = blockIdx.x * 256 + threadIdx.x;
  u32 s1u = 0xFFFFFFFFu, s2u = 0xFFFFFFFFu;
#pragma unroll
  for (int s = 0; s < 8; ++s) {
    const u32 v = scr[s * N_VEC + r];
    const bool lt = v < s1u;
    const u32 c2 = lt ? s1u : v;
    s1u = lt ? v : s1u;
    s2u = c2 < s2u ? c2 : s2u;
  }
  const float s1 = f32_from_sortable(s1u);
  const float s2 = f32_from_sortable(s2u);
  if (s2 - s1 < MARGIN) flag_row(r, count, list, fbit);
}

// ---------------- exact fp64 rescue for flagged rows ----------------
// grid CAP*32: blockIdx>>5 = list slot, blockIdx&31 = 512-code chunk; each wave
// handles 128 codes (64-lane fp64 dot reduce). Rescue keys < any gemm key.
__global__ __launch_bounds__(256) void k_rescue(const float* __restrict__ z,
                                                const float* __restrict__ emb,
                                                const int* __restrict__ count,
                                                const int* __restrict__ list,
                                                u64* __restrict__ fkey) {
  const int li = blockIdx.x >> 5;
  const int chunk = blockIdx.x & 31;
  int cnt = *count; if (cnt > CAP) cnt = CAP;
  if (li >= cnt) return;
  const int row = list[li];
  __shared__ float zl[256];
  const int b = row >> 10, hw = row & 1023;
  zl[threadIdx.x] = z[(b * 256 + threadIdx.x) * 1024 + hw];
  __syncthreads();
  const int lane = threadIdx.x & 63, wvi = threadIdx.x >> 6;
  const int c0 = lane * 4;
  const float z0 = zl[c0], z1 = zl[c0 + 1], z2 = zl[c0 + 2], z3 = zl[c0 + 3];
  u64 local = ~0ull;
  for (int it = 0; it < 128; ++it) {
    const int code = chunk * 512 + wvi * 128 + it;
    const float4 e4 = ((const float4*)emb)[code * 64 + lane];
    double dz = (double)e4.x * z0 + (double)e4.y * z1 + (double)e4.z * z2 + (double)e4.w * z3;
    double de = (double)e4.x * e4.x + (double)e4.y * e4.y + (double)e4.z * e4.z + (double)e4.w * e4.w;
#pragma unroll
    for (int off = 32; off; off >>= 1) { dz += __shfl_down(dz, off); de += __shfl_down(de, off); }
    if (lane == 0) {
      const double sc = de - 2.0 * dz;
      long long qv = (long long)((sc + 1024.0) * 8589934592.0);   // 2^33 fixed point
      if (qv < 0) qv = 0;
      const u64 key = ((u64)qv << 14) | (u32)code;
      if (key < local) local = key;
    }
  }
  if (lane == 0) atomicMin(fkey + row, local);
}

// ---------------- output: z_q (straight-through), loss, indices ----------------
__global__ __launch_bounds__(256) void k_out(const float* __restrict__ z,
                                             const float* __restrict__ emb,
                                             const u64* __restrict__ fkey,
                                             float* __restrict__ out) {
  const int gid = blockIdx.x * 256 + threadIdx.x;   // float4 units
  const int f0 = gid * 4;
  const int bc = f0 >> 10;
  const int hw = f0 & 1023;
  const int c = bc & 255, b = bc >> 8;
  const int n = b * 1024 + hw;
  const float4 z4 = ((const float4*)z)[gid];
  float zz[4] = {z4.x, z4.y, z4.z, z4.w};
  float o[4];
#pragma unroll
  for (int j = 0; j < 4; ++j) {
    const int idx = (int)(fkey[n + j] & 0x3FFFull);
    const float ev = emb[idx * 256 + c];
    o[j] = zz[j] + (ev - zz[j]);
  }
  float4 ov = {o[0], o[1], o[2], o[3]};
  ((float4*)out)[gid] = ov;
  if (gid == 0) out[OUT_LOSS_OFF] = 0.0f;
  if (gid < N_VEC) out[OUT_IDX_OFF + gid] = (float)(u32)(fkey[gid] & 0x3FFFull);
}

extern "C" void kernel_launch(void* const* d_in, const int* in_sizes, int n_in,
                              void* d_out, int out_size, void* d_ws, size_t ws_size,
                              hipStream_t stream) {
  const float* z = (const float*)d_in[0];
  const float* emb = (const float*)d_in[1];
  float* out = (float*)d_out;
  char* ws = (char*)d_ws;

  _Float16* ehi = (_Float16*)(ws + WS_EHI);
  _Float16* elo = (_Float16*)(ws + WS_ELO);
  float* e2 = (float*)(ws + WS_E2);
  u32* scr = (u32*)(ws + WS_SCR);
  u64* fkey = (u64*)(ws + WS_FKEY);
  int* count = (int*)(ws + WS_COUNT);
  int* list = (int*)(ws + WS_LIST);
  u32* fbit = (u32*)(ws + WS_FBIT);

  hipFuncSetAttribute((const void*)k_gemm, hipFuncAttributeMaxDynamicSharedMemorySize,
                      LDS_BYTES);

  k_prep<<<4096, 256, 0, stream>>>(emb, ehi, elo, e2, fkey, fbit, count);
  k_gemm<<<1024, 256, LDS_BYTES, stream>>>(z, ehi, elo, e2, scr, fkey, count, list, fbit);
  k_merge<<<64, 256, 0, stream>>>(scr, fkey, count, list, fbit);
  k_rescue<<<CAP * 32, 256, 0, stream>>>(z, emb, count, list, fkey);
  k_out<<<4096, 256, 0, stream>>>(z, emb, fkey, out);
}

// Round 9
// 984.088 us; speedup vs baseline: 2.8029x; 2.8029x over previous
//
#include <hip/hip_runtime.h>
#include <hip/hip_bf16.h>
#include <stdint.h>

typedef _Float16 f16x8 __attribute__((ext_vector_type(8)));
typedef float f32x4 __attribute__((ext_vector_type(4)));
typedef unsigned long long u64;
typedef unsigned int u32;

#define N_CODES 16384
#define N_VEC   16384

#define OUT_LOSS_OFF 4194304
#define OUT_IDX_OFF  4194305

// ws layout (bytes). High-water mark 17,565,712 B == proven extent. DO NOT GROW.
#define WS_EHI   0u          // 8,388,608
#define WS_ELO   8388608u    // 8,388,608
#define WS_E2    16777216u   // 65,536
#define WS_SCR   16842752u   // u32 [8 splits][16384 rows] = 524,288
#define WS_FKEY  17367040u   // u64 [16384] = 131,072
#define WS_COUNT 17498112u   // 16
#define WS_LIST  17498128u   // 512 ints = 2,048
#define WS_FBIT  17500176u   // 16384 u32 = 65,536 -> ends 17,565,712

#define MARGIN 4.0e-3f
#define CAP 512

#define A_STRIDE 264                        // 256 + 8 pad (f16 units), prologue only
// Loop overlay: S0 slab [0,32K), S1 slab [32K,64K), e2s [64K,72K). Slab = 32 codes
// x 256 k, hi half [0,16K) + lo half [16K,32K), 512 B/code-row, 16B chunks
// XOR-swizzled (chunk ^= row&7) -> every ds phase is 2-way (free, m136).
#define LDS_BYTES 73728                     // -> 2 blocks/CU (147456 <= 163840)

__device__ __forceinline__ u32 sortable_from_f32(float f) {
  u32 u = __float_as_uint(f);
  return (u & 0x80000000u) ? ~u : (u | 0x80000000u);
}
__device__ __forceinline__ float f32_from_sortable(u32 s) {
  u32 u = (s & 0x80000000u) ? (s & 0x7FFFFFFFu) : ~s;
  return __uint_as_float(u);
}

__device__ __forceinline__ void flag_row(int row, int* count, int* list, u32* fbit) {
  if (atomicExch(&fbit[row], 1u) == 0u) {
    const int p = atomicAdd(count, 1);
    if (p < CAP) list[p] = row;
  }
}

// ---------------- prep: embedding -> f16 hi/lo + exact ||e||^2 + state init ----------------
__global__ __launch_bounds__(256) void k_prep(const float* __restrict__ emb,
                                              _Float16* __restrict__ ehi,
                                              _Float16* __restrict__ elo,
                                              float* __restrict__ e2,
                                              u64* __restrict__ fkey,
                                              u32* __restrict__ fbit,
                                              int* __restrict__ count) {
  const int g = blockIdx.x * 256 + threadIdx.x;
  if (g < N_VEC) { fkey[g] = ~0ull; fbit[g] = 0u; }
  if (g == N_VEC) { count[0] = 0; }
  const int code = blockIdx.x * 4 + (threadIdx.x >> 6);
  const int lane = threadIdx.x & 63;
  const float4 v = ((const float4*)emb)[code * 64 + lane];
  union { _Float16 f[4]; uint2 u2; } ph, pl;
  float vv[4] = {v.x, v.y, v.z, v.w};
  double s = 0.0;
#pragma unroll
  for (int j = 0; j < 4; ++j) {
    _Float16 h = (_Float16)vv[j];
    _Float16 l = (_Float16)(vv[j] - (float)h);
    ph.f[j] = h; pl.f[j] = l;
    s += (double)vv[j] * (double)vv[j];
  }
  ((uint2*)ehi)[code * 64 + lane] = ph.u2;
  ((uint2*)elo)[code * 64 + lane] = pl.u2;
#pragma unroll
  for (int off = 32; off; off >>= 1) s += __shfl_down(s, off);
  if (lane == 0) e2[code] = (float)s;
}

// ---------------- main fused GEMM + per-split argmin ----------------
// grid 1024: split = blockIdx & 7 (2048 codes, XCD-pinned), row tile = blockIdx >> 3.
// Tile-granular double-buffered B slabs (32 KB: 32 codes x K=256, hi+lo), ONE barrier
// per tile. 8 uint4 global loads/thread issued one full tile ahead. Epilogue: per-lane
// EXACT f32 top-2 (f1,f2,idx) -- r8's sticky |s-running_min| flag compared against the
// bulk-resident early running min and flagged ~2400 rows (rescue 2.2 ms); the true
// within-lane gap f2-f1 flags only genuine near-ties.
__global__ __launch_bounds__(256, 2) void k_gemm(const float* __restrict__ z,
                                                 const _Float16* __restrict__ ehi,
                                                 const _Float16* __restrict__ elo,
                                                 const float* __restrict__ e2,
                                                 u32* __restrict__ scr,
                                                 u64* __restrict__ fkey,
                                                 int* __restrict__ count,
                                                 int* __restrict__ list,
                                                 u32* __restrict__ fbit) {
  extern __shared__ char smem_raw[];
  _Float16* Asm = (_Float16*)smem_raw;       // prologue A staging (overlaps slabs)
  char* S0 = smem_raw;
  char* S1 = smem_raw + 32768;
  float* e2s = (float*)(smem_raw + 65536);   // 8 KB

  const int tid = threadIdx.x;
  const int split = blockIdx.x & 7;
  const int rt = blockIdx.x >> 3;
  const int row0 = rt * 128;
  const int bb = row0 >> 10, hw0 = row0 & 1023;
  const int cb0 = split * 2048;

  const float4* z4 = (const float4*)z;
  const int lane = tid & 63, w = tid >> 6;
  const int fr = lane & 15, q = lane >> 4;
  const int rbase = w * 32;

  // ---- B staging thread mapping: 4 (row,c) pairs, staged for hi and lo halves ----
  u32 gidx[4], wo[4];
#pragma unroll
  for (int j = 0; j < 4; ++j) {
    const u32 flat = (u32)(j * 256 + tid);   // 0..1023
    const u32 row = flat >> 5;               // 0..31
    const u32 c = flat & 31;                 // 0..31 (16B chunk within row)
    gidx[j] = (u32)(cb0 + (int)row) * 32u + c;             // uint4 units
    wo[j] = row * 512u + ((c ^ (row & 7u)) << 4);          // swizzled byte off in half
  }
  const uint4* EH4 = (const uint4*)ehi;
  const uint4* EL4 = (const uint4*)elo;

  uint4 ph[4], pl[4];
  // tile 0 loads in flight across the whole A prologue
#pragma unroll
  for (int j = 0; j < 4; ++j) { ph[j] = EH4[gidx[j]]; pl[j] = EL4[gidx[j]]; }

  f16x8 ah[2][8], al[2][8];

  // ---- phase 1: stage A-hi tile (128 rows x 256 dims), NCHW transpose ----
  {
    const int fq = tid & 31, cg = tid >> 5;
    for (int i = 0; i < 32; ++i) {
      const int c = i * 8 + cg;
      float4 v = z4[(bb * 256 + c) * 256 + (hw0 >> 2) + fq];
      float vv[4] = {v.x, v.y, v.z, v.w};
      const int r = fq * 4;
#pragma unroll
      for (int j = 0; j < 4; ++j)
        Asm[(r + j) * A_STRIDE + c] = (_Float16)vv[j];
    }
  }
  __syncthreads();
#pragma unroll
  for (int mf = 0; mf < 2; ++mf)
#pragma unroll
    for (int kc = 0; kc < 8; ++kc)
      ah[mf][kc] = *(const f16x8*)&Asm[(rbase + mf * 16 + fr) * A_STRIDE + kc * 32 + q * 8];
  __syncthreads();

  // ---- phase 2: stage A-lo, load fragments ----
  {
    const int fq = tid & 31, cg = tid >> 5;
    for (int i = 0; i < 32; ++i) {
      const int c = i * 8 + cg;
      float4 v = z4[(bb * 256 + c) * 256 + (hw0 >> 2) + fq];
      float vv[4] = {v.x, v.y, v.z, v.w};
      const int r = fq * 4;
#pragma unroll
      for (int j = 0; j < 4; ++j) {
        float f = vv[j];
        _Float16 h = (_Float16)f;
        Asm[(r + j) * A_STRIDE + c] = (_Float16)(f - (float)h);
      }
    }
  }
  __syncthreads();
#pragma unroll
  for (int mf = 0; mf < 2; ++mf)
#pragma unroll
    for (int kc = 0; kc < 8; ++kc)
      al[mf][kc] = *(const f16x8*)&Asm[(rbase + mf * 16 + fr) * A_STRIDE + kc * 32 + q * 8];
  __syncthreads();   // all A reads done before slab/e2 overlay writes

  // ---- overlay prologue: e2 slice, slab 0 commit, tile-1 loads ----
  {
    const float4* e24 = (const float4*)(e2 + cb0);
#pragma unroll
    for (int j = 0; j < 2; ++j)
      ((float4*)e2s)[tid + j * 256] = e24[tid + j * 256];
  }
#pragma unroll
  for (int j = 0; j < 4; ++j) {
    *(uint4*)(S0 + wo[j]) = ph[j];
    *(uint4*)(S0 + 16384 + wo[j]) = pl[j];
  }
#pragma unroll
  for (int j = 0; j < 4; ++j) { ph[j] = EH4[gidx[j] + 1024u]; pl[j] = EL4[gidx[j] + 1024u]; }
  __syncthreads();

  // ---- per-lane argmin state: exact f32 top-2 + best idx ----
  f32x4 acc[2][2] = {};
  float f1[2][4], f2[2][4]; u32 bidx[2][4];
#pragma unroll
  for (int mf = 0; mf < 2; ++mf)
#pragma unroll
    for (int rg = 0; rg < 4; ++rg) { f1[mf][rg] = 1e30f; f2[mf][rg] = 1e30f; bidx[mf][rg] = 0u; }

  // LDS read swizzle precompute: chunk = (kc*4+q) ^ (fr&7), decomposed (no carries)
  const u32 qx = (u32)((q ^ (fr & 3)) << 4);       // low part of swizzled chunk, bytes
  const int kx = (fr >> 2) & 1;                    // flips kc bit0
  const u32 ro0 = (u32)fr * 512u;
  const u32 ro1 = (u32)(fr + 16) * 512u;

  // ---- code sweep: 64 tiles of 32 codes; one barrier per tile ----
  for (int t = 0; t < 64; ++t) {
    const char* Br = (t & 1) ? S1 : S0;
    char* Bw = (t & 1) ? S0 : S1;

    if (t < 63) {
#pragma unroll
      for (int j = 0; j < 4; ++j) {
        *(uint4*)(Bw + wo[j]) = ph[j];
        *(uint4*)(Bw + 16384 + wo[j]) = pl[j];
      }
    }
    if (t < 62) {
      const u32 goff = (u32)(t + 2) * 1024u;
#pragma unroll
      for (int j = 0; j < 4; ++j) { ph[j] = EH4[gidx[j] + goff]; pl[j] = EL4[gidx[j] + goff]; }
    }

#pragma unroll
    for (int kc = 0; kc < 8; ++kc) {
      const u32 off = (u32)(((kc ^ kx) << 6)) + qx;
      const f16x8 bh0 = *(const f16x8*)(Br + ro0 + off);
      const f16x8 bh1 = *(const f16x8*)(Br + ro1 + off);
      const f16x8 bl0 = *(const f16x8*)(Br + 16384 + ro0 + off);
      const f16x8 bl1 = *(const f16x8*)(Br + 16384 + ro1 + off);
      const f16x8 ah0 = ah[0][kc], ah1 = ah[1][kc];
      const f16x8 al0 = al[0][kc], al1 = al[1][kc];

      acc[0][0] = __builtin_amdgcn_mfma_f32_16x16x32_f16(ah0, bh0, acc[0][0], 0, 0, 0);
      acc[0][0] = __builtin_amdgcn_mfma_f32_16x16x32_f16(al0, bh0, acc[0][0], 0, 0, 0);
      acc[0][0] = __builtin_amdgcn_mfma_f32_16x16x32_f16(ah0, bl0, acc[0][0], 0, 0, 0);
      acc[0][1] = __builtin_amdgcn_mfma_f32_16x16x32_f16(ah0, bh1, acc[0][1], 0, 0, 0);
      acc[0][1] = __builtin_amdgcn_mfma_f32_16x16x32_f16(al0, bh1, acc[0][1], 0, 0, 0);
      acc[0][1] = __builtin_amdgcn_mfma_f32_16x16x32_f16(ah0, bl1, acc[0][1], 0, 0, 0);
      acc[1][0] = __builtin_amdgcn_mfma_f32_16x16x32_f16(ah1, bh0, acc[1][0], 0, 0, 0);
      acc[1][0] = __builtin_amdgcn_mfma_f32_16x16x32_f16(al1, bh0, acc[1][0], 0, 0, 0);
      acc[1][0] = __builtin_amdgcn_mfma_f32_16x16x32_f16(ah1, bl0, acc[1][0], 0, 0, 0);
      acc[1][1] = __builtin_amdgcn_mfma_f32_16x16x32_f16(ah1, bh1, acc[1][1], 0, 0, 0);
      acc[1][1] = __builtin_amdgcn_mfma_f32_16x16x32_f16(al1, bh1, acc[1][1], 0, 0, 0);
      acc[1][1] = __builtin_amdgcn_mfma_f32_16x16x32_f16(ah1, bl1, acc[1][1], 0, 0, 0);
    }

    // epilogue: s = ||e||^2 - 2*dot; exact f32 top-2 update per lane.
    // Ascending code order + strict '<' keeps first occurrence; exact duplicates
    // give f2==f1 -> gap 0 < MARGIN -> flagged -> fp64 rescue resolves tie-break.
    {
      const float ev0 = e2s[t * 32 + fr];
      const float ev1 = e2s[t * 32 + 16 + fr];
      const u32 g0 = (u32)(cb0 + t * 32 + fr);
#pragma unroll
      for (int mf = 0; mf < 2; ++mf) {
#pragma unroll
        for (int rg = 0; rg < 4; ++rg) {
          float s0 = fmaf(-2.0f, acc[mf][0][rg], ev0);
          bool lt0 = s0 < f1[mf][rg];
          float c20 = lt0 ? f1[mf][rg] : s0;
          f2[mf][rg] = fminf(f2[mf][rg], c20);
          bidx[mf][rg] = lt0 ? g0 : bidx[mf][rg];
          f1[mf][rg] = lt0 ? s0 : f1[mf][rg];

          float s1 = fmaf(-2.0f, acc[mf][1][rg], ev1);
          bool lt1 = s1 < f1[mf][rg];
          float c21 = lt1 ? f1[mf][rg] : s1;
          f2[mf][rg] = fminf(f2[mf][rg], c21);
          bidx[mf][rg] = lt1 ? (g0 + 16u) : bidx[mf][rg];
          f1[mf][rg] = lt1 ? s1 : f1[mf][rg];
        }
      }
#pragma unroll
      for (int mf = 0; mf < 2; ++mf)
#pragma unroll
        for (int nf = 0; nf < 2; ++nf) acc[mf][nf] = (f32x4){0.0f, 0.0f, 0.0f, 0.0f};
    }

    __syncthreads();   // one barrier/tile: slab write-visibility + read-before-overwrite
  }

  // ---- cross-lane reduce (16 column-lanes): u64 top-2 seeded with (f1,idx),(f2,.) ----
#pragma unroll
  for (int mf = 0; mf < 2; ++mf) {
#pragma unroll
    for (int rg = 0; rg < 4; ++rg) {
      u64 a1 = ((u64)sortable_from_f32(f1[mf][rg]) << 32) | bidx[mf][rg];
      u64 a2 = ((u64)sortable_from_f32(f2[mf][rg]) << 32) | 0xFFFFFFFFull;
#pragma unroll
      for (int off = 1; off < 16; off <<= 1) {
        u64 b1 = __shfl_xor(a1, off);
        u64 b2 = __shfl_xor(a2, off);
        u64 n1 = a1 < b1 ? a1 : b1;
        u64 mx = a1 < b1 ? b1 : a1;
        u64 mn2 = a2 < b2 ? a2 : b2;
        a1 = n1;
        a2 = mx < mn2 ? mx : mn2;
      }
      if (fr == 0) {
        const int row = row0 + rbase + mf * 16 + q * 4 + rg;
        scr[split * N_VEC + row] = (u32)(a1 >> 32);
        atomicMin(&fkey[row], a1);
        const float s1 = f32_from_sortable((u32)(a1 >> 32));
        const float s2 = f32_from_sortable((u32)(a2 >> 32));
        if (s2 - s1 < MARGIN) flag_row(row, count, list, fbit);
      }
    }
  }
}

// ---------------- merge: flag cross-split near-ties (non-destructive) ----------------
// fkey keeps the gemm atomicMin result; rescue keys are numerically always smaller
// than gemm keys, so a rescued row's exact key wins and an un-rescued flagged row
// (CAP overflow) gracefully keeps the gemm argmin.
__global__ __launch_bounds__(256) void k_merge(const u32* __restrict__ scr,
                                               u64* __restrict__ fkey,
                                               int* __restrict__ count,
                                               int* __restrict__ list,
                                               u32* __restrict__ fbit) {
  const int r = blockIdx.x * 256 + threadIdx.x;
  u32 s1u = 0xFFFFFFFFu, s2u = 0xFFFFFFFFu;
#pragma unroll
  for (int s = 0; s < 8; ++s) {
    const u32 v = scr[s * N_VEC + r];
    const bool lt = v < s1u;
    const u32 c2 = lt ? s1u : v;
    s1u = lt ? v : s1u;
    s2u = c2 < s2u ? c2 : s2u;
  }
  const float s1 = f32_from_sortable(s1u);
  const float s2 = f32_from_sortable(s2u);
  if (s2 - s1 < MARGIN) flag_row(r, count, list, fbit);
}

// ---------------- exact fp64 rescue for flagged rows ----------------
// grid CAP*32: blockIdx>>5 = list slot, blockIdx&31 = 512-code chunk; each wave
// handles 128 codes (64-lane fp64 dot reduce). Rescue keys < any gemm key.
__global__ __launch_bounds__(256) void k_rescue(const float* __restrict__ z,
                                                const float* __restrict__ emb,
                                                const int* __restrict__ count,
                                                const int* __restrict__ list,
                                                u64* __restrict__ fkey) {
  const int li = blockIdx.x >> 5;
  const int chunk = blockIdx.x & 31;
  int cnt = *count; if (cnt > CAP) cnt = CAP;
  if (li >= cnt) return;
  const int row = list[li];
  __shared__ float zl[256];
  const int b = row >> 10, hw = row & 1023;
  zl[threadIdx.x] = z[(b * 256 + threadIdx.x) * 1024 + hw];
  __syncthreads();
  const int lane = threadIdx.x & 63, wvi = threadIdx.x >> 6;
  const int c0 = lane * 4;
  const float z0 = zl[c0], z1 = zl[c0 + 1], z2 = zl[c0 + 2], z3 = zl[c0 + 3];
  u64 local = ~0ull;
  for (int it = 0; it < 128; ++it) {
    const int code = chunk * 512 + wvi * 128 + it;
    const float4 e4 = ((const float4*)emb)[code * 64 + lane];
    double dz = (double)e4.x * z0 + (double)e4.y * z1 + (double)e4.z * z2 + (double)e4.w * z3;
    double de = (double)e4.x * e4.x + (double)e4.y * e4.y + (double)e4.z * e4.z + (double)e4.w * e4.w;
#pragma unroll
    for (int off = 32; off; off >>= 1) { dz += __shfl_down(dz, off); de += __shfl_down(de, off); }
    if (lane == 0) {
      const double sc = de - 2.0 * dz;
      long long qv = (long long)((sc + 1024.0) * 8589934592.0);   // 2^33 fixed point
      if (qv < 0) qv = 0;
      const u64 key = ((u64)qv << 14) | (u32)code;
      if (key < local) local = key;
    }
  }
  if (lane == 0) atomicMin(fkey + row, local);
}

// ---------------- output: z_q (straight-through), loss, indices ----------------
__global__ __launch_bounds__(256) void k_out(const float* __restrict__ z,
                                             const float* __restrict__ emb,
                                             const u64* __restrict__ fkey,
                                             float* __restrict__ out) {
  const int gid = blockIdx.x * 256 + threadIdx.x;   // float4 units
  const int f0 = gid * 4;
  const int bc = f0 >> 10;
  const int hw = f0 & 1023;
  const int c = bc & 255, b = bc >> 8;
  const int n = b * 1024 + hw;
  const float4 z4 = ((const float4*)z)[gid];
  float zz[4] = {z4.x, z4.y, z4.z, z4.w};
  float o[4];
#pragma unroll
  for (int j = 0; j < 4; ++j) {
    const int idx = (int)(fkey[n + j] & 0x3FFFull);
    const float ev = emb[idx * 256 + c];
    o[j] = zz[j] + (ev - zz[j]);
  }
  float4 ov = {o[0], o[1], o[2], o[3]};
  ((float4*)out)[gid] = ov;
  if (gid == 0) out[OUT_LOSS_OFF] = 0.0f;
  if (gid < N_VEC) out[OUT_IDX_OFF + gid] = (float)(u32)(fkey[gid] & 0x3FFFull);
}

extern "C" void kernel_launch(void* const* d_in, const int* in_sizes, int n_in,
                              void* d_out, int out_size, void* d_ws, size_t ws_size,
                              hipStream_t stream) {
  const float* z = (const float*)d_in[0];
  const float* emb = (const float*)d_in[1];
  float* out = (float*)d_out;
  char* ws = (char*)d_ws;

  _Float16* ehi = (_Float16*)(ws + WS_EHI);
  _Float16* elo = (_Float16*)(ws + WS_ELO);
  float* e2 = (float*)(ws + WS_E2);
  u32* scr = (u32*)(ws + WS_SCR);
  u64* fkey = (u64*)(ws + WS_FKEY);
  int* count = (int*)(ws + WS_COUNT);
  int* list = (int*)(ws + WS_LIST);
  u32* fbit = (u32*)(ws + WS_FBIT);

  hipFuncSetAttribute((const void*)k_gemm, hipFuncAttributeMaxDynamicSharedMemorySize,
                      LDS_BYTES);

  k_prep<<<4096, 256, 0, stream>>>(emb, ehi, elo, e2, fkey, fbit, count);
  k_gemm<<<1024, 256, LDS_BYTES, stream>>>(z, ehi, elo, e2, scr, fkey, count, list, fbit);
  k_merge<<<64, 256, 0, stream>>>(scr, fkey, count, list, fbit);
  k_rescue<<<CAP * 32, 256, 0, stream>>>(z, emb, count, list, fkey);
  k_out<<<4096, 256, 0, stream>>>(z, emb, fkey, out);
}